// Round 4
// baseline (590.792 us; speedup 1.0000x reference)
//
#include <hip/hip_runtime.h>
#include <hip/hip_bf16.h>

static constexpr int T_STEPS = 512;
static constexpr int NBATCH  = 256;
static constexpr int DD      = 128;                         // C = D = K = 128
static constexpr long TND    = (long)T_STEPS * NBATCH * DD; // elems per output tensor

typedef short bf16x8 __attribute__((ext_vector_type(8)));   // 8 bf16 in 4 VGPRs
typedef float f32x4  __attribute__((ext_vector_type(4)));

// Packed fp32->bf16 (RNE): __float22bfloat162_rn lowers to v_cvt_pk_bf16_f32
// on gfx950 — the scalar bit-twiddle path was ~3 VALU/elem and made the GEMM
// pack-bound (R2 post-mortem). NOTE: __hip_bfloat162 is not trivially
// copyable on this ROCm -> extract bits via __builtin_memcpy, not bit_cast.
__device__ inline void pk2(short* dst, float a, float b) {
  __hip_bfloat162 h = __float22bfloat162_rn(make_float2(a, b));
  short2 s;
  __builtin_memcpy(&s, &h, sizeof(s));
  dst[0] = s.x; dst[1] = s.y;
}
__device__ inline bf16x8 pack8(float4 a, float4 b) {
  short t[8];
  pk2(t + 0, a.x, a.y); pk2(t + 2, a.z, a.w);
  pk2(t + 4, b.x, b.y); pk2(t + 6, b.z, b.w);
  bf16x8 v;
#pragma unroll
  for (int i = 0; i < 8; ++i) v[i] = t[i];
  return v;
}

// ---------------------------------------------------------------------------
// Phase 1 / 3: O[M x 128] = A[M x 128] @ W^T + bias via bf16 MFMA, fp32 accum.
// Wave holds all of W as 32 register-resident B-frags; grid-strides over
// 16-row tiles with next-tile A prefetch held across the MFMA block.
// Layouts (m89/m120-verified): A/B frag [lane&15][quad*8+j]; D col=lane&15,
// row=quad*4+reg.
// ---------------------------------------------------------------------------
__global__ __launch_bounds__(256, 2) void gemm128_mfma(
    const float* __restrict__ A, const float* __restrict__ W,
    const float* __restrict__ bias, float* __restrict__ O, int ntiles) {
  const int lane = threadIdx.x & 63;
  const int wib  = threadIdx.x >> 6;
  const int m    = lane & 15;
  const int q    = lane >> 4;

  bf16x8 Wf[8][4];
#pragma unroll
  for (int j = 0; j < 8; ++j)
#pragma unroll
    for (int kq = 0; kq < 4; ++kq) {
      const float* p = W + (j * 16 + m) * DD + kq * 32 + q * 8;
      Wf[j][kq] = pack8(*(const float4*)p, *(const float4*)(p + 4));
    }
  float bv[8];
#pragma unroll
  for (int j = 0; j < 8; ++j) bv[j] = bias[j * 16 + m];

  int tile = blockIdx.x * 4 + wib;
  const int nw = gridDim.x * 4;
  if (tile >= ntiles) return;

  float4 cur[8];
  {
    const float* ap = A + ((long)tile * 16 + m) * DD + q * 8;
#pragma unroll
    for (int kq = 0; kq < 4; ++kq) {
      cur[2 * kq]     = *(const float4*)(ap + kq * 32);
      cur[2 * kq + 1] = *(const float4*)(ap + kq * 32 + 4);
    }
  }

  for (;;) {
    const int nt   = tile + nw;
    const bool more = nt < ntiles;
    float4 nxt[8];
    if (more) {
      const float* np = A + ((long)nt * 16 + m) * DD + q * 8;
#pragma unroll
      for (int kq = 0; kq < 4; ++kq) {
        nxt[2 * kq]     = *(const float4*)(np + kq * 32);
        nxt[2 * kq + 1] = *(const float4*)(np + kq * 32 + 4);
      }
    }

    f32x4 acc[8];
#pragma unroll
    for (int j = 0; j < 8; ++j) acc[j] = (f32x4){0.f, 0.f, 0.f, 0.f};
#pragma unroll
    for (int kq = 0; kq < 4; ++kq) {
      bf16x8 af = pack8(cur[2 * kq], cur[2 * kq + 1]);
#pragma unroll
      for (int j = 0; j < 8; ++j)
        acc[j] = __builtin_amdgcn_mfma_f32_16x16x32_bf16(af, Wf[j][kq], acc[j], 0, 0, 0);
    }

    const long r0 = (long)tile * 16;
#pragma unroll
    for (int j = 0; j < 8; ++j)
#pragma unroll
      for (int r = 0; r < 4; ++r)
        O[(r0 + q * 4 + r) * DD + j * 16 + m] = acc[j][r] + bv[j];

    if (!more) break;
#pragma unroll
    for (int i = 0; i < 8; ++i) cur[i] = nxt[i];
    tile = nt;
  }
}

// ---------------------------------------------------------------------------
// Phase 2: sequential scan, one block (256 thr / 4 waves) per batch row.
// Thread (c = tid>>4, g = tid&15): owns d-rows c*8..c*8+7 over j-range
// g*8..g*8+7 (64 MACs -> 64 FMA instr/wave, spread on 4 SIMDs vs R2's 256 on
// 2). h broadcast from padded LDS (2 ds_read_b128/thread, conflict-free);
// partials reduced over the 16 g-lanes (xor 1,2 = quad DPP; 4,8 = swizzle).
// Lanes g<8 own output d=c*8+g: cndmask-select a[g], add xp, relu, write.
// Global xp loads / h stores chunked by 8 steps so barrier vmcnt-drain is
// paid per chunk, not per step.
// ---------------------------------------------------------------------------
__global__ __launch_bounds__(256) void rnn_scan(
    const float* __restrict__ Wh, float* __restrict__ H /* [T][N][128] xp->h */) {
  const int tid = threadIdx.x;
  const int g   = tid & 15;
  const int c   = tid >> 4;
  const int n   = blockIdx.x;

  float w[8][8];                      // W_h[c*8+s][g*8+u]
#pragma unroll
  for (int s = 0; s < 8; ++s) {
    const float* p = Wh + (c * 8 + s) * DD + g * 8;
    float4 w0 = *(const float4*)p, w1 = *(const float4*)(p + 4);
    w[s][0] = w0.x; w[s][1] = w0.y; w[s][2] = w0.z; w[s][3] = w0.w;
    w[s][4] = w1.x; w[s][5] = w1.y; w[s][6] = w1.z; w[s][7] = w1.w;
  }

  __shared__ __align__(16) float hb[2][144];   // pos(j) = j + 4*(j>>5)
  for (int i = tid; i < 2 * 144; i += 256) (&hb[0][0])[i] = 0.f;

  const long step = (long)NBATCH * DD;
  const bool wr  = (g < 8);
  const int  d   = c * 8 + g;                  // valid when wr
  const int  dpos = d + 4 * (d >> 5);
  float* gp = H + (long)n * DD + d;            // writer's global column

  float xpc[8], xpn[8], hs[8];
  if (wr) {
#pragma unroll
    for (int i = 0; i < 8; ++i) xpc[i] = gp[(long)i * step];
  }
  __syncthreads();

  const int jadd = g * 8 + 4 * (g >> 2);       // padded read base
  int p = 0;
#pragma unroll 1
  for (int ch = 0; ch < 64; ++ch) {
    const long tn0 = (ch < 63) ? (long)(ch + 1) * 8 : 63L * 8;
    if (wr) {
#pragma unroll
      for (int i = 0; i < 8; ++i) xpn[i] = gp[(tn0 + i) * step];
    }

#pragma unroll
    for (int ti = 0; ti < 8; ++ti) {
      float4 h0 = *(const float4*)&hb[p][jadd];
      float4 h1 = *(const float4*)&hb[p][jadd + 4];
      float a[8];
#pragma unroll
      for (int s = 0; s < 8; ++s)
        a[s] = h0.x * w[s][0] + h0.y * w[s][1] + h0.z * w[s][2] + h0.w * w[s][3]
             + h1.x * w[s][4] + h1.y * w[s][5] + h1.z * w[s][6] + h1.w * w[s][7];
#pragma unroll
      for (int s = 0; s < 8; ++s) {
        a[s] += __shfl_xor(a[s], 1);
        a[s] += __shfl_xor(a[s], 2);
        a[s] += __shfl_xor(a[s], 4);
        a[s] += __shfl_xor(a[s], 8);
      }
      if (wr) {
        float sel = a[0];
#pragma unroll
        for (int s = 1; s < 8; ++s) sel = (g == s) ? a[s] : sel;
        float hv = fmaxf(sel + xpc[ti], 0.f);
        hb[p ^ 1][dpos] = hv;
        hs[ti] = hv;
      }
      __syncthreads();
      p ^= 1;
    }

    if (wr) {
#pragma unroll
      for (int i = 0; i < 8; ++i) gp[(long)(ch * 8 + i) * step] = hs[i];
    }
#pragma unroll
    for (int i = 0; i < 8; ++i) xpc[i] = xpn[i];
  }
}

// ---------------------------------------------------------------------------
extern "C" void kernel_launch(void* const* d_in, const int* in_sizes, int n_in,
                              void* d_out, int out_size, void* d_ws, size_t ws_size,
                              hipStream_t stream) {
  const float* x  = (const float*)d_in[0];   // (T,N,C)
  const float* Wx = (const float*)d_in[1];   // (D,C)
  const float* bx = (const float*)d_in[2];   // (D)
  const float* Wh = (const float*)d_in[3];   // (D,D)
  const float* Wy = (const float*)d_in[4];   // (K,D)
  const float* by = (const float*)d_in[5];   // (K)

  float* Y = (float*)d_out;        // all_y: [T][N][K]
  float* H = (float*)d_out + TND;  // all_h: [T][N][D]

  const int ntiles = T_STEPS * NBATCH / 16;  // 8192 row-tiles

  gemm128_mfma<<<1024, 256, 0, stream>>>(x, Wx, bx, H, ntiles);  // xproj -> H
  rnn_scan<<<NBATCH, 256, 0, stream>>>(Wh, H);                   // in-place xp -> h
  gemm128_mfma<<<1024, 256, 0, stream>>>(H, Wy, by, Y, ntiles);  // all_y
}